// Round 1
// baseline (56.775 us; speedup 1.0000x reference)
//
#include <hip/hip_runtime.h>
#include <math.h>

#define NOUT   10
#define ROWLEN 784           // 28*28
#define WTOT   (NOUT*ROWLEN) // 7840
#define LDSZ   (WTOT + NOUT) // + bias

// ---------------------------------------------------------------------------
// Prep: fold conv + quantum-linear + big linear into one 10x784 matrix + bias.
// logits[b,o] = sum_j x[b,j] * W[o,j] + bias[o]
// ---------------------------------------------------------------------------
__global__ void quanv_prep(const float* __restrict__ conv_w, // (4,1,2,2)
                           const float* __restrict__ conv_b, // (4,)
                           const float* __restrict__ q_w,    // (4,4) (out,in)
                           const float* __restrict__ lin_w,  // (10,1568)
                           const float* __restrict__ lin_b,  // (10,)
                           float* __restrict__ W)            // ws: [7840 W][10 bias]
{
    const int t = threadIdx.x;
    for (int idx = t; idx < WTOT; idx += blockDim.x) {
        const int o = idx / ROWLEN;
        const int j = idx - o * ROWLEN;      // pixel h*28+w
        const int h = j / 28, w = j - h * 28;
        const int p = (h >> 1) * 14 + (w >> 1);      // patch index (196)
        const int k = (h & 1) * 2 + (w & 1);         // pos in 2x2 patch
        float s = 0.f;
        // conv branch: cls_feat index = c*196 + p
        #pragma unroll
        for (int c = 0; c < 4; ++c)
            s += conv_w[c * 4 + k] * lin_w[o * 1568 + c * 196 + p];
        // quantum branch: qfeat index = 784 + p*4 + q
        #pragma unroll
        for (int q = 0; q < 4; ++q)
            s += q_w[q * 4 + k] * lin_w[o * 1568 + 784 + p * 4 + q];
        W[idx] = s;
    }
    if (t < NOUT) {
        float s = lin_b[t];
        #pragma unroll
        for (int c = 0; c < 4; ++c) {
            float cs = 0.f;
            for (int p = 0; p < 196; ++p)
                cs += lin_w[t * 1568 + c * 196 + p];
            s += conv_b[c] * cs;
        }
        W[WTOT + t] = s;
    }
}

// ---------------------------------------------------------------------------
// Main: 8 lanes per row, 2 rows per thread. W broadcast from LDS.
// block = 256 threads = 32 octets -> 64 rows/block. grid = rows/64.
// ---------------------------------------------------------------------------
__global__ __launch_bounds__(256)
void quanv_main(const float* __restrict__ x,
                const float* __restrict__ Wg,   // ws
                float* __restrict__ out,
                int rows)
{
    __shared__ float Wl[LDSZ];
    for (int i = threadIdx.x; i < LDSZ; i += 256) Wl[i] = Wg[i];
    __syncthreads();

    const int t   = threadIdx.x;
    const int l   = t & 7;        // lane in octet
    const int oct = t >> 3;       // 0..31
    const int r0  = blockIdx.x * 64 + oct;
    const int r1  = r0 + 32;

    const float* __restrict__ xr0 = x + (size_t)r0 * ROWLEN;
    const float* __restrict__ xr1 = x + (size_t)r1 * ROWLEN;

    float acc0[NOUT], acc1[NOUT];
    #pragma unroll
    for (int o = 0; o < NOUT; ++o) { acc0[o] = 0.f; acc1[o] = 0.f; }

    // 784 floats = 392 float2; 8 lanes -> 49 iterations, lane l covers
    // float offsets 2*l + 16*i.
    #pragma unroll 7
    for (int i = 0; i < 49; ++i) {
        const int fo = 2 * l + 16 * i;
        const float2 a = *(const float2*)(xr0 + fo);
        const float2 b = *(const float2*)(xr1 + fo);
        #pragma unroll
        for (int o = 0; o < NOUT; ++o) {
            const float2 wv = *(const float2*)&Wl[o * ROWLEN + fo];
            acc0[o] = fmaf(a.x, wv.x, fmaf(a.y, wv.y, acc0[o]));
            acc1[o] = fmaf(b.x, wv.x, fmaf(b.y, wv.y, acc1[o]));
        }
    }

    // reduce across the 8 lanes of the octet
    #pragma unroll
    for (int o = 0; o < NOUT; ++o) {
        acc0[o] += __shfl_xor(acc0[o], 1);
        acc0[o] += __shfl_xor(acc0[o], 2);
        acc0[o] += __shfl_xor(acc0[o], 4);
        acc1[o] += __shfl_xor(acc1[o], 1);
        acc1[o] += __shfl_xor(acc1[o], 2);
        acc1[o] += __shfl_xor(acc1[o], 4);
    }

    if (l == 0) {
        float lg[NOUT];
        // row r0
        float m = -1e30f;
        #pragma unroll
        for (int o = 0; o < NOUT; ++o) { lg[o] = acc0[o] + Wl[WTOT + o]; m = fmaxf(m, lg[o]); }
        float s = 0.f;
        #pragma unroll
        for (int o = 0; o < NOUT; ++o) s += expf(lg[o] - m);
        float lse = m + logf(s);
        #pragma unroll
        for (int o = 0; o < NOUT; ++o) out[(size_t)r0 * NOUT + o] = lg[o] - lse;
        // row r1
        m = -1e30f;
        #pragma unroll
        for (int o = 0; o < NOUT; ++o) { lg[o] = acc1[o] + Wl[WTOT + o]; m = fmaxf(m, lg[o]); }
        s = 0.f;
        #pragma unroll
        for (int o = 0; o < NOUT; ++o) s += expf(lg[o] - m);
        lse = m + logf(s);
        #pragma unroll
        for (int o = 0; o < NOUT; ++o) out[(size_t)r1 * NOUT + o] = lg[o] - lse;
    }
}

extern "C" void kernel_launch(void* const* d_in, const int* in_sizes, int n_in,
                              void* d_out, int out_size, void* d_ws, size_t ws_size,
                              hipStream_t stream) {
    const float* x      = (const float*)d_in[0];
    const float* conv_w = (const float*)d_in[1];
    const float* conv_b = (const float*)d_in[2];
    const float* q_w    = (const float*)d_in[3];
    const float* lin_w  = (const float*)d_in[4];
    const float* lin_b  = (const float*)d_in[5];
    float* out = (float*)d_out;
    float* W   = (float*)d_ws;   // 7850 floats = 31.4 KB

    const int rows = in_sizes[0] / ROWLEN;   // 32768

    quanv_prep<<<1, 256, 0, stream>>>(conv_w, conv_b, q_w, lin_w, lin_b, W);
    quanv_main<<<rows / 64, 256, 0, stream>>>(x, W, out, rows);
}

// Round 2
// 50.174 us; speedup vs baseline: 1.1315x; 1.1315x over previous
//
#include <hip/hip_runtime.h>
#include <math.h>

#define NOUT   10
#define ROWLEN 784           // 28*28
#define WTOT   (NOUT*ROWLEN) // 7840
#define LDSZ   (WTOT + NOUT) // + bias

// ---------------------------------------------------------------------------
// Prep: fold conv + quantum-linear + big linear into one 10x784 matrix + bias.
// logits[b,o] = sum_j x[b,j] * W[o,j] + bias[o]
// Fully parallel — no serial reduction chains.
// ---------------------------------------------------------------------------
__global__ void quanv_prep(const float* __restrict__ conv_w, // (4,1,2,2)
                           const float* __restrict__ conv_b, // (4,)
                           const float* __restrict__ q_w,    // (4,4) (out,in)
                           const float* __restrict__ lin_w,  // (10,1568)
                           const float* __restrict__ lin_b,  // (10,)
                           float* __restrict__ W)            // ws: [7840 W][10 bias]
{
    __shared__ float rs[40];   // rowsum[o][c] = sum_p lin_w[o, c*196+p]
    const int t = threadIdx.x;

    // ---- bias partial sums: 40 (o,c) pairs x 8 lanes, ~25 loads/thread ----
    {
        const int lane = t & 7;
        for (int pair = t >> 3; pair < 40; pair += 32) {
            const int o = pair >> 2, c = pair & 3;
            const float* base = lin_w + o * 1568 + c * 196;
            float s = 0.f;
            #pragma unroll
            for (int p = lane; p < 196; p += 8) s += base[p];
            s += __shfl_xor(s, 1);
            s += __shfl_xor(s, 2);
            s += __shfl_xor(s, 4);
            if (lane == 0) rs[pair] = s;
        }
    }

    // ---- effective weight matrix ----
    for (int idx = t; idx < WTOT; idx += blockDim.x) {
        const int o = idx / ROWLEN;
        const int j = idx - o * ROWLEN;      // pixel h*28+w
        const int h = j / 28, w = j - h * 28;
        const int p = (h >> 1) * 14 + (w >> 1);      // patch index (196)
        const int k = (h & 1) * 2 + (w & 1);         // pos in 2x2 patch
        float s = 0.f;
        #pragma unroll
        for (int c = 0; c < 4; ++c)                  // conv branch
            s += conv_w[c * 4 + k] * lin_w[o * 1568 + c * 196 + p];
        #pragma unroll
        for (int q = 0; q < 4; ++q)                  // quantum branch
            s += q_w[q * 4 + k] * lin_w[o * 1568 + 784 + p * 4 + q];
        W[idx] = s;
    }

    __syncthreads();
    if (t < NOUT) {
        float s = lin_b[t];
        #pragma unroll
        for (int c = 0; c < 4; ++c) s += conv_b[c] * rs[t * 4 + c];
        W[WTOT + t] = s;
    }
}

// ---------------------------------------------------------------------------
// Main: 16 lanes per row, 2 rows per thread. W broadcast from LDS.
// block = 256 threads = 16 groups -> 32 rows/block. grid = rows/32 = 1024.
// 4 blocks/CU (LDS-limited at 5), 16 waves/CU.
// ---------------------------------------------------------------------------
__global__ __launch_bounds__(256)
void quanv_main(const float* __restrict__ x,
                const float* __restrict__ Wg,   // ws
                float* __restrict__ out,
                int rows)
{
    __shared__ float Wl[LDSZ];
    for (int i = threadIdx.x; i < LDSZ; i += 256) Wl[i] = Wg[i];
    __syncthreads();

    const int t  = threadIdx.x;
    const int l  = t & 15;        // lane in group
    const int g  = t >> 4;        // group 0..15
    const int r0 = blockIdx.x * 32 + g;
    const int r1 = r0 + 16;

    const float* __restrict__ xr0 = x + (size_t)r0 * ROWLEN;
    const float* __restrict__ xr1 = x + (size_t)r1 * ROWLEN;

    float acc0[NOUT], acc1[NOUT];
    #pragma unroll
    for (int o = 0; o < NOUT; ++o) { acc0[o] = 0.f; acc1[o] = 0.f; }

    // 784 floats; 16 lanes x float2 = 32 floats/iter -> 24 full iters + tail.
    #pragma unroll 4
    for (int i = 0; i < 24; ++i) {
        const int fo = 2 * l + 32 * i;
        const float2 a = *(const float2*)(xr0 + fo);
        const float2 b = *(const float2*)(xr1 + fo);
        #pragma unroll
        for (int o = 0; o < NOUT; ++o) {
            const float2 wv = *(const float2*)&Wl[o * ROWLEN + fo];
            acc0[o] = fmaf(a.x, wv.x, fmaf(a.y, wv.y, acc0[o]));
            acc1[o] = fmaf(b.x, wv.x, fmaf(b.y, wv.y, acc1[o]));
        }
    }
    // tail: floats 768..783 (lanes 0..7 only)
    if (l < 8) {
        const int fo = 2 * l + 768;
        const float2 a = *(const float2*)(xr0 + fo);
        const float2 b = *(const float2*)(xr1 + fo);
        #pragma unroll
        for (int o = 0; o < NOUT; ++o) {
            const float2 wv = *(const float2*)&Wl[o * ROWLEN + fo];
            acc0[o] = fmaf(a.x, wv.x, fmaf(a.y, wv.y, acc0[o]));
            acc1[o] = fmaf(b.x, wv.x, fmaf(b.y, wv.y, acc1[o]));
        }
    }

    // full butterfly over the 16 lanes: every lane ends with the totals
    #pragma unroll
    for (int o = 0; o < NOUT; ++o) {
        acc0[o] += __shfl_xor(acc0[o], 1);
        acc0[o] += __shfl_xor(acc0[o], 2);
        acc0[o] += __shfl_xor(acc0[o], 4);
        acc0[o] += __shfl_xor(acc0[o], 8);
        acc1[o] += __shfl_xor(acc1[o], 1);
        acc1[o] += __shfl_xor(acc1[o], 2);
        acc1[o] += __shfl_xor(acc1[o], 4);
        acc1[o] += __shfl_xor(acc1[o], 8);
    }

    // lane 0 finishes row r0, lane 1 finishes row r1 (parallel epilogues)
    if (l < 2) {
        const int   r   = (l == 0) ? r0 : r1;
        const float* ac = (l == 0) ? acc0 : acc1;
        float lg[NOUT];
        float m = -1e30f;
        #pragma unroll
        for (int o = 0; o < NOUT; ++o) { lg[o] = ac[o] + Wl[WTOT + o]; m = fmaxf(m, lg[o]); }
        float s = 0.f;
        #pragma unroll
        for (int o = 0; o < NOUT; ++o) s += expf(lg[o] - m);
        const float lse = m + logf(s);
        float* op = out + (size_t)r * NOUT;
        #pragma unroll
        for (int o = 0; o < NOUT; o += 2) {
            float2 v = make_float2(lg[o] - lse, lg[o + 1] - lse);
            *(float2*)(op + o) = v;
        }
    }
}

extern "C" void kernel_launch(void* const* d_in, const int* in_sizes, int n_in,
                              void* d_out, int out_size, void* d_ws, size_t ws_size,
                              hipStream_t stream) {
    const float* x      = (const float*)d_in[0];
    const float* conv_w = (const float*)d_in[1];
    const float* conv_b = (const float*)d_in[2];
    const float* q_w    = (const float*)d_in[3];
    const float* lin_w  = (const float*)d_in[4];
    const float* lin_b  = (const float*)d_in[5];
    float* out = (float*)d_out;
    float* W   = (float*)d_ws;   // 7850 floats = 31.4 KB

    const int rows = in_sizes[0] / ROWLEN;   // 32768

    quanv_prep<<<1, 256, 0, stream>>>(conv_w, conv_b, q_w, lin_w, lin_b, W);
    quanv_main<<<rows / 32, 256, 0, stream>>>(x, W, out, rows);
}

// Round 3
// 38.441 us; speedup vs baseline: 1.4769x; 1.3052x over previous
//
#include <hip/hip_runtime.h>
#include <math.h>

#define NOUT   10
#define ROWLEN 784           // 28*28
#define WTOT   (NOUT*ROWLEN) // 7840

// ---------------------------------------------------------------------------
// Single fused kernel. The whole net is affine until log_softmax:
//   logits[b,o] = sum_j x[b,j]*Weff[o,j] + beff[o]
// Each block folds conv_w/conv_b/q_w/lin_w/lin_b into Weff (10x784) + beff
// directly in its own LDS (lin_w is L2-resident; ~3us, parallel across all
// blocks), then streams its 32 rows of x with float4 loads.
// Layout: 16 lanes per row-pair, 2 adjacent rows per thread.
// __launch_bounds__(256,4): 4 blocks/CU, LDS 4*31.6KB = 126KB < 160KB.
// ---------------------------------------------------------------------------
__global__ __launch_bounds__(256, 4)
void quanv_fused(const float* __restrict__ x,
                 const float* __restrict__ conv_w, // (4,1,2,2)
                 const float* __restrict__ conv_b, // (4,)
                 const float* __restrict__ q_w,    // (4,4) (out,in)
                 const float* __restrict__ lin_w,  // (10,1568)
                 const float* __restrict__ lin_b,  // (10,)
                 float* __restrict__ out)
{
    __shared__ float Wl[WTOT];
    __shared__ float bias[NOUT];
    __shared__ float rs[40];   // rowsum[o][c] = sum_p lin_w[o, c*196+p]

    const int t = threadIdx.x;

    // ---- Phase A: bias rowsums (8-lane octets, ~25 independent loads each) ----
    {
        const int lane = t & 7;
        for (int pair = t >> 3; pair < 40; pair += 32) {
            const int o = pair >> 2, c = pair & 3;
            const float* base = lin_w + o * 1568 + c * 196;
            float s = 0.f;
            #pragma unroll
            for (int p = 0; p < 196; p += 8) {
                const int pp = p + lane;
                if (pp < 196) s += base[pp];
            }
            s += __shfl_xor(s, 1);
            s += __shfl_xor(s, 2);
            s += __shfl_xor(s, 4);
            if (lane == 0) rs[pair] = s;
        }
    }

    // ---- Phase B: effective weight matrix into LDS ----
    for (int idx = t; idx < WTOT; idx += 256) {
        const int o = idx / ROWLEN;
        const int j = idx - o * ROWLEN;          // pixel h*28+w
        const int h = j / 28, w = j - h * 28;
        const int p = (h >> 1) * 14 + (w >> 1);  // patch index (196)
        const int k = (h & 1) * 2 + (w & 1);     // pos in 2x2 patch
        float s = 0.f;
        #pragma unroll
        for (int c = 0; c < 4; ++c)              // conv branch
            s += conv_w[c * 4 + k] * lin_w[o * 1568 + c * 196 + p];
        #pragma unroll
        for (int q = 0; q < 4; ++q)              // quantum branch
            s += q_w[q * 4 + k] * lin_w[o * 1568 + 784 + p * 4 + q];
        Wl[idx] = s;
    }

    __syncthreads();
    if (t < NOUT) {
        float s = lin_b[t];
        #pragma unroll
        for (int c = 0; c < 4; ++c) s += conv_b[c] * rs[t * 4 + c];
        bias[t] = s;
    }
    __syncthreads();

    // ---- Phase C: stream 32 rows. 16 lanes/row-pair, float4 loads. ----
    const int l  = t & 15;
    const int g  = t >> 4;
    const int r0 = blockIdx.x * 32 + 2 * g;      // adjacent rows r0, r0+1

    const float* __restrict__ xr0 = x + (size_t)r0 * ROWLEN;
    const float* __restrict__ xr1 = xr0 + ROWLEN;

    float acc0[NOUT], acc1[NOUT];
    #pragma unroll
    for (int o = 0; o < NOUT; ++o) { acc0[o] = 0.f; acc1[o] = 0.f; }

    // 784 floats = 196 float4; 16 lanes/iter -> 12 full iters + 4-chunk tail.
    float4 a = *(const float4*)(xr0 + 4 * l);
    float4 b = *(const float4*)(xr1 + 4 * l);

    #pragma unroll 3
    for (int i = 0; i < 12; ++i) {
        float4 an, bn;
        if (i < 11) {
            const int nfo = 4 * l + 64 * (i + 1);
            an = *(const float4*)(xr0 + nfo);
            bn = *(const float4*)(xr1 + nfo);
        } else {
            const int tfo = 768 + 4 * (l & 3);   // tail chunk (valid addr all lanes)
            an = *(const float4*)(xr0 + tfo);
            bn = *(const float4*)(xr1 + tfo);
        }
        const int fo = 4 * l + 64 * i;
        #pragma unroll
        for (int o = 0; o < NOUT; ++o) {
            const float4 wv = *(const float4*)&Wl[o * ROWLEN + fo];
            acc0[o] = fmaf(a.x, wv.x, fmaf(a.y, wv.y, fmaf(a.z, wv.z, fmaf(a.w, wv.w, acc0[o]))));
            acc1[o] = fmaf(b.x, wv.x, fmaf(b.y, wv.y, fmaf(b.z, wv.z, fmaf(b.w, wv.w, acc1[o]))));
        }
        a = an; b = bn;
    }
    // tail: floats 768..783, lanes 0..3 hold distinct chunks in a/b
    if (l < 4) {
        const int fo = 768 + 4 * l;
        #pragma unroll
        for (int o = 0; o < NOUT; ++o) {
            const float4 wv = *(const float4*)&Wl[o * ROWLEN + fo];
            acc0[o] = fmaf(a.x, wv.x, fmaf(a.y, wv.y, fmaf(a.z, wv.z, fmaf(a.w, wv.w, acc0[o]))));
            acc1[o] = fmaf(b.x, wv.x, fmaf(b.y, wv.y, fmaf(b.z, wv.z, fmaf(b.w, wv.w, acc1[o]))));
        }
    }

    // full butterfly over 16 lanes: every lane ends with the row totals
    #pragma unroll
    for (int o = 0; o < NOUT; ++o) {
        acc0[o] += __shfl_xor(acc0[o], 1);
        acc0[o] += __shfl_xor(acc0[o], 2);
        acc0[o] += __shfl_xor(acc0[o], 4);
        acc0[o] += __shfl_xor(acc0[o], 8);
        acc1[o] += __shfl_xor(acc1[o], 1);
        acc1[o] += __shfl_xor(acc1[o], 2);
        acc1[o] += __shfl_xor(acc1[o], 4);
        acc1[o] += __shfl_xor(acc1[o], 8);
    }

    // log-softmax (computed redundantly by all lanes; no runtime-indexed
    // register arrays — select own element via cndmask chain)
    float lg0[NOUT], lg1[NOUT];
    float m0 = -1e30f, m1 = -1e30f;
    #pragma unroll
    for (int o = 0; o < NOUT; ++o) {
        lg0[o] = acc0[o] + bias[o]; m0 = fmaxf(m0, lg0[o]);
        lg1[o] = acc1[o] + bias[o]; m1 = fmaxf(m1, lg1[o]);
    }
    float s0 = 0.f, s1 = 0.f;
    #pragma unroll
    for (int o = 0; o < NOUT; ++o) {
        s0 += expf(lg0[o] - m0);
        s1 += expf(lg1[o] - m1);
    }
    const float lse0 = m0 + logf(s0);
    const float lse1 = m1 + logf(s1);

    if (l < NOUT) {
        float v0 = lg0[0], v1 = lg1[0];
        #pragma unroll
        for (int o = 1; o < NOUT; ++o) {
            v0 = (l == o) ? lg0[o] : v0;
            v1 = (l == o) ? lg1[o] : v1;
        }
        out[(size_t)r0 * NOUT + l]       = v0 - lse0;   // lanes 0..9: 40B runs,
        out[(size_t)(r0 + 1) * NOUT + l] = v1 - lse1;   // contiguous per group
    }
}

extern "C" void kernel_launch(void* const* d_in, const int* in_sizes, int n_in,
                              void* d_out, int out_size, void* d_ws, size_t ws_size,
                              hipStream_t stream) {
    const float* x      = (const float*)d_in[0];
    const float* conv_w = (const float*)d_in[1];
    const float* conv_b = (const float*)d_in[2];
    const float* q_w    = (const float*)d_in[3];
    const float* lin_w  = (const float*)d_in[4];
    const float* lin_b  = (const float*)d_in[5];
    float* out = (float*)d_out;

    const int rows = in_sizes[0] / ROWLEN;   // 32768
    quanv_fused<<<rows / 32, 256, 0, stream>>>(x, conv_w, conv_b, q_w,
                                               lin_w, lin_b, out);
}

// Round 4
// 32.226 us; speedup vs baseline: 1.7618x; 1.1929x over previous
//
#include <hip/hip_runtime.h>
#include <math.h>

#define NOUT   10
#define ROWLEN 784           // 28*28
#define WTOT   (NOUT*ROWLEN) // 7840

// ---------------------------------------------------------------------------
// Prep: fold conv+quantum+linear into Weff (10x784) + bias, into d_ws.
// Parallel across 31 blocks; bias rowsums in block 0 (8-lane octet reduce).
// ---------------------------------------------------------------------------
__global__ __launch_bounds__(256)
void quanv_prep(const float* __restrict__ conv_w, // (4,1,2,2)
                const float* __restrict__ conv_b, // (4,)
                const float* __restrict__ q_w,    // (4,4) (out,in)
                const float* __restrict__ lin_w,  // (10,1568)
                const float* __restrict__ lin_b,  // (10,)
                float* __restrict__ W)            // ws: [7840 W][10 bias]
{
    const int t = threadIdx.x;

    for (int idx = blockIdx.x * 256 + t; idx < WTOT; idx += gridDim.x * 256) {
        const int o = idx / ROWLEN;
        const int j = idx - o * ROWLEN;          // pixel h*28+w
        const int h = j / 28, w = j - h * 28;
        const int p = (h >> 1) * 14 + (w >> 1);  // patch index (196)
        const int k = (h & 1) * 2 + (w & 1);     // pos in 2x2 patch
        float s = 0.f;
        #pragma unroll
        for (int c = 0; c < 4; ++c)              // conv branch
            s += conv_w[c * 4 + k] * lin_w[o * 1568 + c * 196 + p];
        #pragma unroll
        for (int q = 0; q < 4; ++q)              // quantum branch
            s += q_w[q * 4 + k] * lin_w[o * 1568 + 784 + p * 4 + q];
        W[idx] = s;
    }

    if (blockIdx.x == 0) {
        __shared__ float rs[40];                 // rowsum[o][c]
        const int lane = t & 7;
        for (int pair = t >> 3; pair < 40; pair += 32) {
            const int o = pair >> 2, c = pair & 3;
            const float* base = lin_w + o * 1568 + c * 196;
            float s = 0.f;
            #pragma unroll
            for (int p = 0; p < 196; p += 8) {
                const int pp = p + lane;
                if (pp < 196) s += base[pp];
            }
            s += __shfl_xor(s, 1);
            s += __shfl_xor(s, 2);
            s += __shfl_xor(s, 4);
            if (lane == 0) rs[pair] = s;
        }
        __syncthreads();
        if (t < NOUT) {
            float s = lin_b[t];
            #pragma unroll
            for (int c = 0; c < 4; ++c) s += conv_b[c] * rs[t * 4 + c];
            W[WTOT + t] = s;
        }
    }
}

// ---------------------------------------------------------------------------
// Main: coalesced float4 LDS fill of Weff, then stream x.
// 16 lanes per row-pair, 2 adjacent rows/thread, depth-2 prefetch
// (4 outstanding 16B loads per thread). Fully unrolled so the prefetch
// double-buffer uses compile-time indices only.
// __launch_bounds__(256,4): 4 blocks/CU (LDS 4*31.4KB), 16 waves/CU.
// ---------------------------------------------------------------------------
__global__ __launch_bounds__(256, 4)
void quanv_main(const float* __restrict__ x,
                const float* __restrict__ Wg,   // ws
                float* __restrict__ out)
{
    __shared__ float Wl[WTOT];
    __shared__ float bias[NOUT];

    {   // coalesced fill: 1960 float4 over 256 threads
        const float4* __restrict__ src = (const float4*)Wg;
        float4* dst = (float4*)Wl;
        #pragma unroll
        for (int i = 0; i < 8; ++i) {
            const int idx = threadIdx.x + 256 * i;
            if (idx < WTOT / 4) dst[idx] = src[idx];
        }
        if (threadIdx.x < NOUT) bias[threadIdx.x] = Wg[WTOT + threadIdx.x];
    }
    __syncthreads();

    const int t  = threadIdx.x;
    const int l  = t & 15;
    const int g  = t >> 4;
    const int r0 = blockIdx.x * 32 + 2 * g;      // adjacent rows r0, r0+1

    const float* __restrict__ xr0 = x + (size_t)r0 * ROWLEN;
    const float* __restrict__ xr1 = xr0 + ROWLEN;

    float acc0[NOUT], acc1[NOUT];
    #pragma unroll
    for (int o = 0; o < NOUT; ++o) { acc0[o] = 0.f; acc1[o] = 0.f; }

    // chunk for iter i: floats [4l + 64i, +4); 12 iters cover 0..767.
    // tail chunk 768..783 handled by lanes 0..3.
    float4 pa0 = *(const float4*)(xr0 + 4 * l);
    float4 pb0 = *(const float4*)(xr1 + 4 * l);
    float4 pa1 = *(const float4*)(xr0 + 4 * l + 64);
    float4 pb1 = *(const float4*)(xr1 + 4 * l + 64);

    #pragma unroll
    for (int i = 0; i < 12; ++i) {
        float4 a, b;
        if ((i & 1) == 0) { a = pa0; b = pb0; } else { a = pa1; b = pb1; }

        const int ni = i + 2;                    // prefetch into consumed buffer
        if (ni < 12) {
            const int nfo = 4 * l + 64 * ni;
            if ((i & 1) == 0) {
                pa0 = *(const float4*)(xr0 + nfo);
                pb0 = *(const float4*)(xr1 + nfo);
            } else {
                pa1 = *(const float4*)(xr0 + nfo);
                pb1 = *(const float4*)(xr1 + nfo);
            }
        } else if (ni == 12) {                   // i==10, parity 0 -> pa0/pb0
            const int tfo = 768 + 4 * (l & 3);
            pa0 = *(const float4*)(xr0 + tfo);
            pb0 = *(const float4*)(xr1 + tfo);
        }

        const int fo = 4 * l + 64 * i;
        #pragma unroll
        for (int o = 0; o < NOUT; ++o) {
            const float4 wv = *(const float4*)&Wl[o * ROWLEN + fo];
            acc0[o] = fmaf(a.x, wv.x, fmaf(a.y, wv.y, fmaf(a.z, wv.z, fmaf(a.w, wv.w, acc0[o]))));
            acc1[o] = fmaf(b.x, wv.x, fmaf(b.y, wv.y, fmaf(b.z, wv.z, fmaf(b.w, wv.w, acc1[o]))));
        }
    }
    // tail: floats 768..783 live in pa0/pb0 (loaded at i==10)
    if (l < 4) {
        const int fo = 768 + 4 * l;
        #pragma unroll
        for (int o = 0; o < NOUT; ++o) {
            const float4 wv = *(const float4*)&Wl[o * ROWLEN + fo];
            acc0[o] = fmaf(pa0.x, wv.x, fmaf(pa0.y, wv.y, fmaf(pa0.z, wv.z, fmaf(pa0.w, wv.w, acc0[o]))));
            acc1[o] = fmaf(pb0.x, wv.x, fmaf(pb0.y, wv.y, fmaf(pb0.z, wv.z, fmaf(pb0.w, wv.w, acc1[o]))));
        }
    }

    // full butterfly over 16 lanes: every lane ends with the row totals
    #pragma unroll
    for (int o = 0; o < NOUT; ++o) {
        acc0[o] += __shfl_xor(acc0[o], 1);
        acc0[o] += __shfl_xor(acc0[o], 2);
        acc0[o] += __shfl_xor(acc0[o], 4);
        acc0[o] += __shfl_xor(acc0[o], 8);
        acc1[o] += __shfl_xor(acc1[o], 1);
        acc1[o] += __shfl_xor(acc1[o], 2);
        acc1[o] += __shfl_xor(acc1[o], 4);
        acc1[o] += __shfl_xor(acc1[o], 8);
    }

    // log-softmax, redundantly on all lanes; lane<10 stores own element
    float lg0[NOUT], lg1[NOUT];
    float m0 = -1e30f, m1 = -1e30f;
    #pragma unroll
    for (int o = 0; o < NOUT; ++o) {
        lg0[o] = acc0[o] + bias[o]; m0 = fmaxf(m0, lg0[o]);
        lg1[o] = acc1[o] + bias[o]; m1 = fmaxf(m1, lg1[o]);
    }
    float s0 = 0.f, s1 = 0.f;
    #pragma unroll
    for (int o = 0; o < NOUT; ++o) {
        s0 += expf(lg0[o] - m0);
        s1 += expf(lg1[o] - m1);
    }
    const float lse0 = m0 + logf(s0);
    const float lse1 = m1 + logf(s1);

    if (l < NOUT) {
        float v0 = lg0[0], v1 = lg1[0];
        #pragma unroll
        for (int o = 1; o < NOUT; ++o) {
            v0 = (l == o) ? lg0[o] : v0;
            v1 = (l == o) ? lg1[o] : v1;
        }
        out[(size_t)r0 * NOUT + l]       = v0 - lse0;
        out[(size_t)(r0 + 1) * NOUT + l] = v1 - lse1;
    }
}

extern "C" void kernel_launch(void* const* d_in, const int* in_sizes, int n_in,
                              void* d_out, int out_size, void* d_ws, size_t ws_size,
                              hipStream_t stream) {
    const float* x      = (const float*)d_in[0];
    const float* conv_w = (const float*)d_in[1];
    const float* conv_b = (const float*)d_in[2];
    const float* q_w    = (const float*)d_in[3];
    const float* lin_w  = (const float*)d_in[4];
    const float* lin_b  = (const float*)d_in[5];
    float* out = (float*)d_out;
    float* W   = (float*)d_ws;   // 7850 floats = 31.4 KB

    const int rows = in_sizes[0] / ROWLEN;   // 32768

    quanv_prep<<<31, 256, 0, stream>>>(conv_w, conv_b, q_w, lin_w, lin_b, W);
    quanv_main<<<rows / 32, 256, 0, stream>>>(x, W, out);
}

// Round 5
// 31.896 us; speedup vs baseline: 1.7800x; 1.0103x over previous
//
#include <hip/hip_runtime.h>
#include <math.h>

#define NOUT   10
#define ROWLEN 784           // 28*28
#define WTOT   (NOUT*ROWLEN) // 7840

// ---------------------------------------------------------------------------
// Prep: fold conv+quantum+linear into Weff (10x784) + bias, into d_ws.
// ---------------------------------------------------------------------------
__global__ __launch_bounds__(256)
void quanv_prep(const float* __restrict__ conv_w, // (4,1,2,2)
                const float* __restrict__ conv_b, // (4,)
                const float* __restrict__ q_w,    // (4,4) (out,in)
                const float* __restrict__ lin_w,  // (10,1568)
                const float* __restrict__ lin_b,  // (10,)
                float* __restrict__ W)            // ws: [7840 W][10 bias]
{
    const int t = threadIdx.x;

    for (int idx = blockIdx.x * 256 + t; idx < WTOT; idx += gridDim.x * 256) {
        const int o = idx / ROWLEN;
        const int j = idx - o * ROWLEN;          // pixel h*28+w
        const int h = j / 28, w = j - h * 28;
        const int p = (h >> 1) * 14 + (w >> 1);  // patch index (196)
        const int k = (h & 1) * 2 + (w & 1);     // pos in 2x2 patch
        float s = 0.f;
        #pragma unroll
        for (int c = 0; c < 4; ++c)              // conv branch
            s += conv_w[c * 4 + k] * lin_w[o * 1568 + c * 196 + p];
        #pragma unroll
        for (int q = 0; q < 4; ++q)              // quantum branch
            s += q_w[q * 4 + k] * lin_w[o * 1568 + 784 + p * 4 + q];
        W[idx] = s;
    }

    if (blockIdx.x == 0) {
        __shared__ float rs[40];                 // rowsum[o][c]
        const int lane = t & 7;
        for (int pair = t >> 3; pair < 40; pair += 32) {
            const int o = pair >> 2, c = pair & 3;
            const float* base = lin_w + o * 1568 + c * 196;
            float s = 0.f;
            #pragma unroll
            for (int p = 0; p < 196; p += 8) {
                const int pp = p + lane;
                if (pp < 196) s += base[pp];
            }
            s += __shfl_xor(s, 1);
            s += __shfl_xor(s, 2);
            s += __shfl_xor(s, 4);
            if (lane == 0) rs[pair] = s;
        }
        __syncthreads();
        if (t < NOUT) {
            float s = lin_b[t];
            #pragma unroll
            for (int c = 0; c < 4; ++c) s += conv_b[c] * rs[t * 4 + c];
            W[WTOT + t] = s;
        }
    }
}

// ---------------------------------------------------------------------------
// Main. Split-output layout: each 32-lane pair handles 4 adjacent rows;
// lower 16 lanes (gp=0) accumulate outputs 0..4, upper 16 (gp=1) outputs
// 5..9. Halves the ds_read_b128 count per row vs the broadcast layout.
// Wave = 2 pairs = 8 rows; block = 4 waves = 32 rows; grid = 1024.
// Depth-2 prefetch, 4 rows/thread -> 8 outstanding 16B loads.
// ---------------------------------------------------------------------------
__global__ __launch_bounds__(256, 4)
void quanv_main(const float* __restrict__ x,
                const float* __restrict__ Wg,   // ws
                float* __restrict__ out)
{
    __shared__ float Wl[WTOT];
    __shared__ float bias[NOUT];

    const int t     = threadIdx.x;
    const int lane  = t & 63;
    const int wv    = t >> 6;          // wave in block
    const int l     = lane & 15;       // lane in 16-group
    const int grp   = lane >> 4;       // 0..3
    const int pair  = grp >> 1;        // 0,1
    const int gp    = grp & 1;         // output-half selector
    const int obase = gp * 5;
    const int r0    = blockIdx.x * 32 + wv * 8 + pair * 4;

    const float* __restrict__ xr = x + (size_t)r0 * ROWLEN;

    // issue initial x prefetch BEFORE the LDS fill (independent work)
    float4 px0[4], px1[4];
    #pragma unroll
    for (int r = 0; r < 4; ++r) {
        px0[r] = *(const float4*)(xr + r * ROWLEN + 4 * l);
        px1[r] = *(const float4*)(xr + r * ROWLEN + 4 * l + 64);
    }

    {   // coalesced LDS fill: 1960 float4 over 256 threads
        const float4* __restrict__ src = (const float4*)Wg;
        float4* dst = (float4*)Wl;
        #pragma unroll
        for (int i = 0; i < 8; ++i) {
            const int idx = t + 256 * i;
            if (idx < WTOT / 4) dst[idx] = src[idx];
        }
        if (t < NOUT) bias[t] = Wg[WTOT + t];
    }
    __syncthreads();

    float acc[4][5];
    #pragma unroll
    for (int r = 0; r < 4; ++r)
        #pragma unroll
        for (int o = 0; o < 5; ++o) acc[r][o] = 0.f;

    const int wb = obase * ROWLEN;

    #pragma unroll
    for (int i = 0; i < 12; ++i) {
        float4 cur[4];
        #pragma unroll
        for (int r = 0; r < 4; ++r) cur[r] = ((i & 1) == 0) ? px0[r] : px1[r];

        const int ni = i + 2;                    // prefetch into consumed buffer
        if (ni < 12) {
            const int nfo = 4 * l + 64 * ni;
            #pragma unroll
            for (int r = 0; r < 4; ++r) {
                const float4 v = *(const float4*)(xr + r * ROWLEN + nfo);
                if ((i & 1) == 0) px0[r] = v; else px1[r] = v;
            }
        } else if (ni == 12) {                   // i==10 -> tail into px0
            const int tfo = 768 + 4 * (l & 3);
            #pragma unroll
            for (int r = 0; r < 4; ++r)
                px0[r] = *(const float4*)(xr + r * ROWLEN + tfo);
        }

        const int fo = 4 * l + 64 * i;
        #pragma unroll
        for (int o = 0; o < 5; ++o) {
            const float4 w4 = *(const float4*)&Wl[wb + o * ROWLEN + fo];
            #pragma unroll
            for (int r = 0; r < 4; ++r)
                acc[r][o] = fmaf(cur[r].x, w4.x, fmaf(cur[r].y, w4.y,
                            fmaf(cur[r].z, w4.z, fmaf(cur[r].w, w4.w, acc[r][o]))));
        }
    }
    // tail: floats 768..783 (in px0, loaded at i==10); lanes 0..3 only
    if (l < 4) {
        const int fo = 768 + 4 * l;
        #pragma unroll
        for (int o = 0; o < 5; ++o) {
            const float4 w4 = *(const float4*)&Wl[wb + o * ROWLEN + fo];
            #pragma unroll
            for (int r = 0; r < 4; ++r)
                acc[r][o] = fmaf(px0[r].x, w4.x, fmaf(px0[r].y, w4.y,
                            fmaf(px0[r].z, w4.z, fmaf(px0[r].w, w4.w, acc[r][o]))));
        }
    }

    // butterfly over the 16-lane group: every lane gets the group totals
    #pragma unroll
    for (int r = 0; r < 4; ++r)
        #pragma unroll
        for (int o = 0; o < 5; ++o) {
            acc[r][o] += __shfl_xor(acc[r][o], 1);
            acc[r][o] += __shfl_xor(acc[r][o], 2);
            acc[r][o] += __shfl_xor(acc[r][o], 4);
            acc[r][o] += __shfl_xor(acc[r][o], 8);
        }

    // add own-half bias, exchange with the partner half (xor 16)
    float own[4][5], part[4][5];
    #pragma unroll
    for (int r = 0; r < 4; ++r)
        #pragma unroll
        for (int o = 0; o < 5; ++o) {
            own[r][o]  = acc[r][o] + bias[obase + o];
            part[r][o] = __shfl_xor(own[r][o], 16);
        }

    // this lane finishes rows (2*gp, 2*gp+1); build full 10-logit vectors
    // (all register indices compile-time; gp-selects are cndmask)
    float lgA[10], lgB[10];
    #pragma unroll
    for (int o = 0; o < 5; ++o) {
        lgA[o]     = gp ? part[2][o] : own[0][o];
        lgA[o + 5] = gp ? own[2][o]  : part[0][o];
        lgB[o]     = gp ? part[3][o] : own[1][o];
        lgB[o + 5] = gp ? own[3][o]  : part[1][o];
    }

    float mA = -1e30f, mB = -1e30f;
    #pragma unroll
    for (int o = 0; o < 10; ++o) { mA = fmaxf(mA, lgA[o]); mB = fmaxf(mB, lgB[o]); }
    float sA = 0.f, sB = 0.f;
    #pragma unroll
    for (int o = 0; o < 10; ++o) { sA += expf(lgA[o] - mA); sB += expf(lgB[o] - mB); }
    const float lseA = mA + logf(sA);
    const float lseB = mB + logf(sB);

    if (l < NOUT) {
        float vA = lgA[0], vB = lgB[0];
        #pragma unroll
        for (int o = 1; o < 10; ++o) {
            vA = (l == o) ? lgA[o] : vA;
            vB = (l == o) ? lgB[o] : vB;
        }
        const int rA = r0 + 2 * gp;
        out[(size_t)rA * NOUT + l]       = vA - lseA;
        out[(size_t)(rA + 1) * NOUT + l] = vB - lseB;
    }
}

extern "C" void kernel_launch(void* const* d_in, const int* in_sizes, int n_in,
                              void* d_out, int out_size, void* d_ws, size_t ws_size,
                              hipStream_t stream) {
    const float* x      = (const float*)d_in[0];
    const float* conv_w = (const float*)d_in[1];
    const float* conv_b = (const float*)d_in[2];
    const float* q_w    = (const float*)d_in[3];
    const float* lin_w  = (const float*)d_in[4];
    const float* lin_b  = (const float*)d_in[5];
    float* out = (float*)d_out;
    float* W   = (float*)d_ws;   // 7850 floats = 31.4 KB

    const int rows = in_sizes[0] / ROWLEN;   // 32768

    quanv_prep<<<31, 256, 0, stream>>>(conv_w, conv_b, q_w, lin_w, lin_b, W);
    quanv_main<<<rows / 32, 256, 0, stream>>>(x, W, out);
}